// Round 6
// baseline (161.771 us; speedup 1.0000x reference)
//
#include <hip/hip_runtime.h>
#include <hip/hip_bf16.h>

// Two sudoku graphs per block. bf16 MFMA throughout.
// S = (A+I) symmetric, deg==21 -> norm = 1/21 for every edge.
// Rolled-loop structure (layer loop + kc loops) to keep code small and
// I$-resident; accumulator zero-init via peeled kc=0 MFMA with C=0.
typedef __attribute__((ext_vector_type(8))) short bf16x8;
typedef __attribute__((ext_vector_type(4))) float f32x4;

__device__ __forceinline__ unsigned short f2b(float f) {
    __hip_bfloat16 h = __float2bfloat16(f);
    return __builtin_bit_cast(unsigned short, h);
}
__device__ __forceinline__ float b2f(unsigned short u) {
    unsigned v = ((unsigned)u) << 16;
    return __builtin_bit_cast(float, v);
}
__device__ __forceinline__ float ldf(const void* p, int idx, bool f32) {
    return f32 ? ((const float*)p)[idx] : b2f(((const unsigned short*)p)[idx]);
}
__device__ __forceinline__ unsigned short ldb(const void* p, int idx, bool f32) {
    return f32 ? f2b(((const float*)p)[idx]) : ((const unsigned short*)p)[idx];
}

// dtype sniff from a uniform 64B of x (fp32 mantissa ushorts -> wild exponents)
__device__ __forceinline__ bool sniff_f32(const void* x) {
    const unsigned* p = (const unsigned*)x;
    int wild = 0;
#pragma unroll
    for (int i = 0; i < 16; ++i) {
        unsigned e = (p[i] >> 7) & 0xFF;
        wild += (e != 0 && (e < 0x68 || e > 0x90)) ? 1 : 0;
    }
    return wild > 8;
}

// ---- ws layout (bytes) ----
#define WS_B1F    16        // 128 f32
#define WS_B2F    528       // 128 f32
#define WS_BHF    1040      // 104 f32
#define WS_W1R    1536      // 128*32 bf16   [f][k]
#define WS_W2R    9728      // 128*128 bf16  [f][k]
#define WS_SR     42496     // 18*64*8 bf16  [(mi*3+kc)*64+lane][j]
#define WS_WH     60928     // 104*128 f32   [o][f]

__global__ void k_repack(const void* __restrict__ x,
                         const void* __restrict__ W1, const void* __restrict__ b1,
                         const void* __restrict__ W2, const void* __restrict__ b2,
                         const void* __restrict__ Wa, const void* __restrict__ ba,
                         const void* __restrict__ Wc, const void* __restrict__ bc,
                         const void* __restrict__ Wn, const void* __restrict__ bn,
                         const void* __restrict__ Wt, const void* __restrict__ bt,
                         char* __restrict__ ws) {
    const bool f32 = sniff_f32(x);
    int idx = blockIdx.x * blockDim.x + threadIdx.x;
    if (idx < 4096) {                         // w1r [f][k]
        int f = idx >> 5, k = idx & 31;
        unsigned short v = (k < 10) ? ldb(W1, k * 128 + f, f32) : (unsigned short)0;
        ((unsigned short*)(ws + WS_W1R))[idx] = v;
        return;
    }
    idx -= 4096;
    if (idx < 16384) {                        // w2r [f][k]
        int f = idx >> 7, k = idx & 127;
        ((unsigned short*)(ws + WS_W2R))[idx] = ldb(W2, k * 128 + f, f32);
        return;
    }
    idx -= 16384;
    if (idx < 9216) {                         // S fragments
        int fi = idx >> 9, rem = idx & 511;
        int lane = rem >> 3, j = rem & 7;
        int mi = fi / 3, kc = fi - mi * 3;
        int node = mi * 16 + (lane & 15);
        int cell = kc * 32 + ((lane >> 4) << 3) + j;
        bool adj = false;
        if (node < 81 && cell < 81) {
            int ni = node / 9, nj = node % 9;
            int ci = cell / 9, cj = cell % 9;
            adj = (ni == ci) || (nj == cj) ||
                  ((ni / 3 == ci / 3) && (nj / 3 == cj / 3));
        }
        ((unsigned short*)(ws + WS_SR))[idx] = adj ? (unsigned short)0x3F80 : (unsigned short)0;
        return;
    }
    idx -= 9216;
    if (idx < 13312) {                        // head weights (f32) [o][f]
        int o = idx >> 7, f = idx & 127;
        const void* W; int oo, dim;
        if (o < 4)       { W = Wa; oo = o;      dim = 4;  }
        else if (o < 85) { W = Wc; oo = o - 4;  dim = 81; }
        else if (o < 94) { W = Wn; oo = o - 85; dim = 9;  }
        else             { W = Wt; oo = o - 94; dim = 10; }
        ((float*)(ws + WS_WH))[idx] = ldf(W, f * dim + oo, f32);
        return;
    }
    idx -= 13312;
    if (idx < 360) {                          // biases
        float v;
        if (idx < 128)      v = ldf(b1, idx, f32);
        else if (idx < 256) v = ldf(b2, idx - 128, f32);
        else {
            int o = idx - 256;
            if (o < 4)       v = ldf(ba, o, f32);
            else if (o < 85) v = ldf(bc, o - 4, f32);
            else if (o < 94) v = ldf(bn, o - 85, f32);
            else             v = ldf(bt, o - 94, f32);
        }
        if (idx < 128)      ((float*)(ws + WS_B1F))[idx] = v;
        else if (idx < 256) ((float*)(ws + WS_B2F))[idx - 128] = v;
        else                ((float*)(ws + WS_BHF))[idx - 256] = v;
    }
}

#define TS 104   // t^T view: [f:128][cell:96], rows 208B (16B-aligned)
#define HS 136   // h view:   [node:96][f:128], rows 272B (16B-aligned)

__global__ __launch_bounds__(256, 2) void sudoku_gnn(
    const void* __restrict__ x, const char* __restrict__ ws,
    void* __restrict__ out, int nB)
{
    __shared__ __attribute__((aligned(16))) unsigned short sG[2][13312]; // t^T / h aliased
    __shared__ float sPoolPart[2][256];
    __shared__ float sPool[2][128];

    const bool f32 = sniff_f32(x);
    const unsigned short* w1r = (const unsigned short*)(ws + WS_W1R);
    const unsigned short* w2r = (const unsigned short*)(ws + WS_W2R);
    const unsigned short* sr  = (const unsigned short*)(ws + WS_SR);
    const float* b1f = (const float*)(ws + WS_B1F);
    const float* b2f = (const float*)(ws + WS_B2F);
    const float* bhf = (const float*)(ws + WS_BHF);
    const float* whf = (const float*)(ws + WS_WH);

    const int tid  = threadIdx.x;
    const int wave = tid >> 6;
    const int lane = tid & 63;
    const int ln15 = lane & 15;
    const int q    = lane >> 4;
    const int k0   = q * 8;
    const int mtb  = (wave & 1) * 3;      // node-half tiles
    const int nb   = (wave & 1) * 48;
    const int fb   = (wave >> 1) * 64;    // feature half
    const int g0   = blockIdx.x * 2;
    const bool hasB = (g0 + 1 < nB);
    const int g1   = hasB ? (g0 + 1) : g0;   // clamp (no OOB)
    const float inv21 = 1.0f / 21.0f;

    // ---- persistent S fragments (B-operand; S symmetric) ----
    bf16x8 sfr[3][3];
#pragma unroll
    for (int kc = 0; kc < 3; ++kc)
#pragma unroll
        for (int jt = 0; jt < 3; ++jt)
            sfr[kc][jt] = *(const bf16x8*)&sr[(((mtb + jt) * 3 + kc) * 64 + lane) * 8];

    // ---- stage x into h-layout LDS (rows 0..95, cols 0..31, zero-padded) ----
#pragma unroll 1
    for (int idx = tid; idx < 96 * 16 * 2; idx += 256) {
        int gg  = idx >= 96 * 16;
        int r   = idx - gg * 96 * 16;
        int row = r >> 4, col = (r & 15) * 2;
        int g   = gg ? g1 : g0;
        unsigned short v0 = 0, v1 = 0;
        if (row < 81) {
            int base = (g * 81 + row) * 10;
            if (col < 10)     v0 = ldb(x, base + col, f32);
            if (col + 1 < 10) v1 = ldb(x, base + col + 1, f32);
        }
        *(unsigned*)&sG[gg][row * HS + col] = (unsigned)v0 | ((unsigned)v1 << 16);
    }
    __syncthreads();

    const f32x4 z4 = {0.f, 0.f, 0.f, 0.f};
    f32x4 acc[2][3][4];

    // ================= layer loop (rolled) =================
#pragma unroll 1
    for (int l = 0; l < 2; ++l) {
        const unsigned short* w = l ? w2r : w1r;
        const int ldw = l ? 128 : 32;
        const int kcn = l ? 4 : 1;

        // ---- GEMM: t = h @ W ; kc=0 peeled (acc init) ----
        {
            bf16x8 wf[4], a3[2][3];
#pragma unroll
            for (int nt = 0; nt < 4; ++nt)
                wf[nt] = *(const bf16x8*)&w[(fb + nt * 16 + ln15) * ldw + k0];
#pragma unroll
            for (int gg = 0; gg < 2; ++gg)
#pragma unroll
                for (int mt = 0; mt < 3; ++mt)
                    a3[gg][mt] = *(const bf16x8*)&sG[gg][((mtb + mt) * 16 + ln15) * HS + k0];
#pragma unroll
            for (int gg = 0; gg < 2; ++gg)
#pragma unroll
                for (int mt = 0; mt < 3; ++mt)
#pragma unroll
                    for (int nt = 0; nt < 4; ++nt)
                        acc[gg][mt][nt] = __builtin_amdgcn_mfma_f32_16x16x32_bf16(a3[gg][mt], wf[nt], z4, 0, 0, 0);
        }
#pragma unroll 1
        for (int kc = 1; kc < kcn; ++kc) {
            bf16x8 wf[4], a3[2][3];
#pragma unroll
            for (int nt = 0; nt < 4; ++nt)
                wf[nt] = *(const bf16x8*)&w[(fb + nt * 16 + ln15) * ldw + kc * 32 + k0];
#pragma unroll
            for (int gg = 0; gg < 2; ++gg)
#pragma unroll
                for (int mt = 0; mt < 3; ++mt)
                    a3[gg][mt] = *(const bf16x8*)&sG[gg][((mtb + mt) * 16 + ln15) * HS + kc * 32 + k0];
#pragma unroll
            for (int gg = 0; gg < 2; ++gg)
#pragma unroll
                for (int mt = 0; mt < 3; ++mt)
#pragma unroll
                    for (int nt = 0; nt < 4; ++nt)
                        acc[gg][mt][nt] = __builtin_amdgcn_mfma_f32_16x16x32_bf16(a3[gg][mt], wf[nt], acc[gg][mt][nt], 0, 0, 0);
        }
        __syncthreads();   // h reads done before aliased t^T writes

        // ---- write t^T[f][cell] (b64 per lane) ----
#pragma unroll
        for (int gg = 0; gg < 2; ++gg)
#pragma unroll
            for (int mt = 0; mt < 3; ++mt)
#pragma unroll
                for (int nt = 0; nt < 4; ++nt) {
                    int f = fb + nt * 16 + ln15;
                    int cellb = (mtb + mt) * 16 + q * 4;
                    unsigned lo = (unsigned)f2b(acc[gg][mt][nt][0]) | ((unsigned)f2b(acc[gg][mt][nt][1]) << 16);
                    unsigned hi = (unsigned)f2b(acc[gg][mt][nt][2]) | ((unsigned)f2b(acc[gg][mt][nt][3]) << 16);
                    *(uint2*)&sG[gg][f * TS + cellb] = make_uint2(lo, hi);
                }
        __syncthreads();

        // ---- AGG: h^T = t^T @ S ; kc=0 peeled (acc init) ----
        {
            bf16x8 a4[2][4];
#pragma unroll
            for (int gg = 0; gg < 2; ++gg)
#pragma unroll
                for (int at = 0; at < 4; ++at)
                    a4[gg][at] = *(const bf16x8*)&sG[gg][(fb + at * 16 + ln15) * TS + k0];
#pragma unroll
            for (int gg = 0; gg < 2; ++gg)
#pragma unroll
                for (int at = 0; at < 4; ++at)
#pragma unroll
                    for (int jt = 0; jt < 3; ++jt)
                        acc[gg][jt][at] = __builtin_amdgcn_mfma_f32_16x16x32_bf16(a4[gg][at], sfr[0][jt], z4, 0, 0, 0);
        }
#pragma unroll 1
        for (int kc = 1; kc < 3; ++kc) {
            bf16x8 a4[2][4];
#pragma unroll
            for (int gg = 0; gg < 2; ++gg)
#pragma unroll
                for (int at = 0; at < 4; ++at)
                    a4[gg][at] = *(const bf16x8*)&sG[gg][(fb + at * 16 + ln15) * TS + kc * 32 + k0];
#pragma unroll
            for (int gg = 0; gg < 2; ++gg)
#pragma unroll
                for (int at = 0; at < 4; ++at)
#pragma unroll
                    for (int jt = 0; jt < 3; ++jt)
                        acc[gg][jt][at] = __builtin_amdgcn_mfma_f32_16x16x32_bf16(a4[gg][at], sfr[kc][jt], acc[gg][jt][at], 0, 0, 0);
        }
        __syncthreads();   // t^T reads done before aliased h writes

        if (l == 0) {
            // ---- epilogue: h = relu(agg/21 + b1) -> h[node][f] ----
#pragma unroll
            for (int gg = 0; gg < 2; ++gg)
#pragma unroll
                for (int at = 0; at < 4; ++at) {
                    float4 bv = *(const float4*)&b1f[fb + at * 16 + q * 4];
#pragma unroll
                    for (int jt = 0; jt < 3; ++jt) {
                        int node = nb + jt * 16 + ln15;
                        float v0 = fmaxf(acc[gg][jt][at][0] * inv21 + bv.x, 0.0f);
                        float v1 = fmaxf(acc[gg][jt][at][1] * inv21 + bv.y, 0.0f);
                        float v2 = fmaxf(acc[gg][jt][at][2] * inv21 + bv.z, 0.0f);
                        float v3 = fmaxf(acc[gg][jt][at][3] * inv21 + bv.w, 0.0f);
                        unsigned lo = (unsigned)f2b(v0) | ((unsigned)f2b(v1) << 16);
                        unsigned hi = (unsigned)f2b(v2) | ((unsigned)f2b(v3) << 16);
                        *(uint2*)&sG[gg][node * HS + fb + at * 16 + q * 4] = make_uint2(lo, hi);
                    }
                }
            __syncthreads();
        } else {
            // ---- epilogue: relu(agg/21 + b2), mean-pool over nodes ----
#pragma unroll
            for (int gg = 0; gg < 2; ++gg)
#pragma unroll
                for (int at = 0; at < 4; ++at) {
                    float4 bv = *(const float4*)&b2f[fb + at * 16 + q * 4];
                    float s0 = 0.f, s1 = 0.f, s2 = 0.f, s3 = 0.f;
#pragma unroll
                    for (int jt = 0; jt < 3; ++jt) {
                        int node = nb + jt * 16 + ln15;
                        if (node < 81) {
                            s0 += fmaxf(acc[gg][jt][at][0] * inv21 + bv.x, 0.0f);
                            s1 += fmaxf(acc[gg][jt][at][1] * inv21 + bv.y, 0.0f);
                            s2 += fmaxf(acc[gg][jt][at][2] * inv21 + bv.z, 0.0f);
                            s3 += fmaxf(acc[gg][jt][at][3] * inv21 + bv.w, 0.0f);
                        }
                    }
#pragma unroll
                    for (int off = 1; off < 16; off <<= 1) {
                        s0 += __shfl_xor(s0, off);
                        s1 += __shfl_xor(s1, off);
                        s2 += __shfl_xor(s2, off);
                        s3 += __shfl_xor(s3, off);
                    }
                    if (ln15 == 0) {
                        float4 v = {s0, s1, s2, s3};
                        *(float4*)&sPoolPart[gg][(wave & 1) * 128 + fb + at * 16 + q * 4] = v;
                    }
                }
            __syncthreads();
            {
                int gg = tid >> 7, f = tid & 127;
                sPool[gg][f] = (sPoolPart[gg][f] + sPoolPart[gg][128 + f]) * (1.0f / 81.0f);
            }
            __syncthreads();
        }
    }

    // ---------- heads (104 outputs per graph; A on tids 0..127, B on 128..255) ----------
    {
        int gg = tid >> 7;
        int o  = tid & 127;
        int g  = gg ? (g0 + 1) : g0;
        if (o < 104 && (gg == 0 || hasB)) {
            float a = bhf[o];
            const float4* wrow = (const float4*)(whf + o * 128);
            const float4* sp4  = (const float4*)sPool[gg];
#pragma unroll 8
            for (int i = 0; i < 32; ++i) {
                float4 wv = wrow[i];
                float4 pv = sp4[i];
                a += pv.x * wv.x + pv.y * wv.y + pv.z * wv.z + pv.w * wv.w;
            }
            int oo; size_t off;
            if (o < 4)       { oo = o;      off = (size_t)g * 4 + oo; }
            else if (o < 85) { oo = o - 4;  off = (size_t)nB * 4  + (size_t)g * 81 + oo; }
            else if (o < 94) { oo = o - 85; off = (size_t)nB * 85 + (size_t)g * 9  + oo; }
            else             { oo = o - 94; off = (size_t)nB * 94 + (size_t)g * 10 + oo; }
            if (f32) ((float*)out)[off] = a;
            else     ((unsigned short*)out)[off] = f2b(a);
        }
    }
}

extern "C" void kernel_launch(void* const* d_in, const int* in_sizes, int n_in,
                              void* d_out, int out_size, void* d_ws, size_t ws_size,
                              hipStream_t stream) {
    // setup_inputs order: x, edge_index, batch, W1, b1, W2, b2, Wa, ba, Wc, bc, Wn, bn, Wt, bt
    const void* x  = d_in[0];
    int nB = in_sizes[2] / 81;
    if (nB <= 0) return;

    char* ws = (char*)d_ws;
    hipLaunchKernelGGL(k_repack, dim3(170), dim3(256), 0, stream,
                       x, d_in[3], d_in[4], d_in[5], d_in[6],
                       d_in[7], d_in[8], d_in[9], d_in[10],
                       d_in[11], d_in[12], d_in[13], d_in[14], ws);
    hipLaunchKernelGGL(sudoku_gnn, dim3((nB + 1) / 2), dim3(256), 0, stream,
                       x, (const char*)ws, d_out, nB);
}

// Round 7
// 154.153 us; speedup vs baseline: 1.0494x; 1.0494x over previous
//
#include <hip/hip_runtime.h>
#include <hip/hip_bf16.h>

// One sudoku graph per 128-thread block (2 waves, f-split). bf16 MFMA.
// S = (A+I) symmetric, deg==21 -> 1/21 folded into W1/W2 at repack; 1/81
// (mean-pool) folded into head weights. Dataflow (layout-optimal chain):
//   GEMM1 x@W1' -> t1^T[f][cell] -> AGG1 t1^T@S -> h[node][f] (relu+b1)
//   GEMM2 h@W2' -> t2^T[f][cell] -> AGG2 t2^T@S -> pool -> heads
// Every producer->consumer handoff is a b64 write / b128 read in LDS.
// 2-wave barriers + ~5 independent blocks/CU break the 4-wave phase convoy.
typedef __attribute__((ext_vector_type(8))) short bf16x8;
typedef __attribute__((ext_vector_type(4))) float f32x4;

__device__ __forceinline__ unsigned short f2b(float f) {
    __hip_bfloat16 h = __float2bfloat16(f);
    return __builtin_bit_cast(unsigned short, h);
}
__device__ __forceinline__ float b2f(unsigned short u) {
    unsigned v = ((unsigned)u) << 16;
    return __builtin_bit_cast(float, v);
}
__device__ __forceinline__ float ldf(const void* p, int idx, bool f32) {
    return f32 ? ((const float*)p)[idx] : b2f(((const unsigned short*)p)[idx]);
}
__device__ __forceinline__ unsigned short ldb(const void* p, int idx, bool f32) {
    return f32 ? f2b(((const float*)p)[idx]) : ((const unsigned short*)p)[idx];
}
// branchless RNE pack of two finite floats -> bf16x2 (no NaN guard needed)
__device__ __forceinline__ unsigned packRNE(float x, float y) {
    unsigned a = __builtin_bit_cast(unsigned, x);
    unsigned b = __builtin_bit_cast(unsigned, y);
    a += 0x7fffu + ((a >> 16) & 1u);
    b += 0x7fffu + ((b >> 16) & 1u);
    return (a >> 16) | (b & 0xffff0000u);
}

// dtype sniff from a uniform 64B of x (fp32 mantissa ushorts -> wild exponents)
__device__ __forceinline__ bool sniff_f32(const void* x) {
    const unsigned* p = (const unsigned*)x;
    int wild = 0;
#pragma unroll
    for (int i = 0; i < 16; ++i) {
        unsigned e = (p[i] >> 7) & 0xFF;
        wild += (e != 0 && (e < 0x68 || e > 0x90)) ? 1 : 0;
    }
    return wild > 8;
}

// ---- ws layout (bytes) ----
#define WS_B1F    16        // 128 f32
#define WS_B2F    528       // 128 f32
#define WS_BHF    1040      // 104 f32
#define WS_W1R    1536      // 128*32 bf16   [f][k]   (pre-scaled 1/21)
#define WS_W2R    9728      // 128*128 bf16  [f][k]   (pre-scaled 1/21)
#define WS_SR     42496     // 18*64*8 bf16  [(jt*3+kc)*64+lane][j]
#define WS_WH     60928     // 104*128 f32   [o][f]   (pre-scaled 1/81)

__global__ void k_repack(const void* __restrict__ x,
                         const void* __restrict__ W1, const void* __restrict__ b1,
                         const void* __restrict__ W2, const void* __restrict__ b2,
                         const void* __restrict__ Wa, const void* __restrict__ ba,
                         const void* __restrict__ Wc, const void* __restrict__ bc,
                         const void* __restrict__ Wn, const void* __restrict__ bn,
                         const void* __restrict__ Wt, const void* __restrict__ bt,
                         char* __restrict__ ws) {
    const bool f32 = sniff_f32(x);
    const float inv21 = 1.0f / 21.0f;
    int idx = blockIdx.x * blockDim.x + threadIdx.x;
    if (idx < 4096) {                         // w1r [f][k], scaled 1/21
        int f = idx >> 5, k = idx & 31;
        unsigned short v = (k < 10) ? f2b(ldf(W1, k * 128 + f, f32) * inv21) : (unsigned short)0;
        ((unsigned short*)(ws + WS_W1R))[idx] = v;
        return;
    }
    idx -= 4096;
    if (idx < 16384) {                        // w2r [f][k], scaled 1/21
        int f = idx >> 7, k = idx & 127;
        ((unsigned short*)(ws + WS_W2R))[idx] = f2b(ldf(W2, k * 128 + f, f32) * inv21);
        return;
    }
    idx -= 16384;
    if (idx < 9216) {                         // S fragments
        int fi = idx >> 9, rem = idx & 511;
        int lane = rem >> 3, j = rem & 7;
        int mi = fi / 3, kc = fi - mi * 3;
        int node = mi * 16 + (lane & 15);
        int cell = kc * 32 + ((lane >> 4) << 3) + j;
        bool adj = false;
        if (node < 81 && cell < 81) {
            int ni = node / 9, nj = node % 9;
            int ci = cell / 9, cj = cell % 9;
            adj = (ni == ci) || (nj == cj) ||
                  ((ni / 3 == ci / 3) && (nj / 3 == cj / 3));
        }
        ((unsigned short*)(ws + WS_SR))[idx] = adj ? (unsigned short)0x3F80 : (unsigned short)0;
        return;
    }
    idx -= 9216;
    if (idx < 13312) {                        // head weights (f32), scaled 1/81
        int o = idx >> 7, f = idx & 127;
        const void* W; int oo, dim;
        if (o < 4)       { W = Wa; oo = o;      dim = 4;  }
        else if (o < 85) { W = Wc; oo = o - 4;  dim = 81; }
        else if (o < 94) { W = Wn; oo = o - 85; dim = 9;  }
        else             { W = Wt; oo = o - 94; dim = 10; }
        ((float*)(ws + WS_WH))[idx] = ldf(W, f * dim + oo, f32) * (1.0f / 81.0f);
        return;
    }
    idx -= 13312;
    if (idx < 360) {                          // biases (unscaled)
        float v;
        if (idx < 128)      v = ldf(b1, idx, f32);
        else if (idx < 256) v = ldf(b2, idx - 128, f32);
        else {
            int o = idx - 256;
            if (o < 4)       v = ldf(ba, o, f32);
            else if (o < 85) v = ldf(bc, o - 4, f32);
            else if (o < 94) v = ldf(bn, o - 85, f32);
            else             v = ldf(bt, o - 94, f32);
        }
        if (idx < 128)      ((float*)(ws + WS_B1F))[idx] = v;
        else if (idx < 256) ((float*)(ws + WS_B2F))[idx - 128] = v;
        else                ((float*)(ws + WS_BHF))[idx - 256] = v;
    }
}

#define TS 104   // t^T view: [f:128][cell:96+8]   13312 shorts
#define HS 136   // h view:   [node:96][f:128+8]   13056 shorts (aliased)

__global__ __launch_bounds__(128, 3) void sudoku_gnn(
    const void* __restrict__ x, const char* __restrict__ ws,
    void* __restrict__ out, int nB)
{
    __shared__ __attribute__((aligned(16))) unsigned short sG[13312]; // t^T / h aliased
    __shared__ float sPool[128];

    const bool f32 = sniff_f32(x);
    const unsigned short* w1r = (const unsigned short*)(ws + WS_W1R);
    const unsigned short* w2r = (const unsigned short*)(ws + WS_W2R);
    const unsigned short* sr  = (const unsigned short*)(ws + WS_SR);
    const float* b1f = (const float*)(ws + WS_B1F);
    const float* b2f = (const float*)(ws + WS_B2F);
    const float* bhf = (const float*)(ws + WS_BHF);
    const float* whf = (const float*)(ws + WS_WH);

    const int tid  = threadIdx.x;               // 128 threads = 2 waves
    const int wave = tid >> 6;
    const int lane = tid & 63;
    const int ln15 = lane & 15;
    const int q    = lane >> 4;
    const int k0   = q * 8;
    const int fb   = wave * 64;                 // feature half per wave
    const int g    = blockIdx.x;

    // ---- x A-frags straight from global (one-time; q>=2 lanes are K-pad) ----
    bf16x8 xf[6];
#pragma unroll
    for (int mt = 0; mt < 6; ++mt) {
        int node = mt * 16 + ln15;
        bf16x8 v = {0, 0, 0, 0, 0, 0, 0, 0};
        if (node < 81) {
            int base = (g * 81 + node) * 10;
            if (q == 0) {
#pragma unroll
                for (int jj = 0; jj < 8; ++jj) v[jj] = (short)ldb(x, base + jj, f32);
            } else if (q == 1) {
                v[0] = (short)ldb(x, base + 8, f32);
                v[1] = (short)ldb(x, base + 9, f32);
            }
        }
        xf[mt] = v;
    }
    // W1' B-frags (pre-scaled)
    bf16x8 w1f[4];
#pragma unroll
    for (int nt = 0; nt < 4; ++nt)
        w1f[nt] = *(const bf16x8*)&w1r[(fb + nt * 16 + ln15) * 32 + k0];

    const f32x4 z4 = {0.f, 0.f, 0.f, 0.f};
    f32x4 acc[6][4];   // GEMM: [mt][nt]; AGG: [jt][at]

    // ---------- GEMM1: t1 = x @ W1' ; write t1^T[f][cell] ----------
#pragma unroll
    for (int mt = 0; mt < 6; ++mt)
#pragma unroll
        for (int nt = 0; nt < 4; ++nt)
            acc[mt][nt] = __builtin_amdgcn_mfma_f32_16x16x32_bf16(xf[mt], w1f[nt], z4, 0, 0, 0);
#pragma unroll
    for (int mt = 0; mt < 6; ++mt)
#pragma unroll
        for (int nt = 0; nt < 4; ++nt) {
            int f = fb + nt * 16 + ln15;
            int cellb = mt * 16 + q * 4;
            *(uint2*)&sG[f * TS + cellb] =
                make_uint2(packRNE(acc[mt][nt][0], acc[mt][nt][1]),
                           packRNE(acc[mt][nt][2], acc[mt][nt][3]));
        }
    __syncthreads();   // (1)

    // ---------- AGG1: h1^T = t1^T @ S ----------
#pragma unroll
    for (int kc = 0; kc < 3; ++kc) {
        bf16x8 afr[4], sfb[6];
#pragma unroll
        for (int at = 0; at < 4; ++at)
            afr[at] = *(const bf16x8*)&sG[(fb + at * 16 + ln15) * TS + kc * 32 + k0];
#pragma unroll
        for (int jt = 0; jt < 6; ++jt)
            sfb[jt] = *(const bf16x8*)&sr[((jt * 3 + kc) * 64 + lane) * 8];
        if (kc == 0) {
#pragma unroll
            for (int jt = 0; jt < 6; ++jt)
#pragma unroll
                for (int at = 0; at < 4; ++at)
                    acc[jt][at] = __builtin_amdgcn_mfma_f32_16x16x32_bf16(afr[at], sfb[jt], z4, 0, 0, 0);
        } else {
#pragma unroll
            for (int jt = 0; jt < 6; ++jt)
#pragma unroll
                for (int at = 0; at < 4; ++at)
                    acc[jt][at] = __builtin_amdgcn_mfma_f32_16x16x32_bf16(afr[at], sfb[jt], acc[jt][at], 0, 0, 0);
        }
    }
    __syncthreads();   // (2) t1^T reads done before aliased h writes

    // epilogue: h = relu(agg + b1)  (1/21 folded into W1')
#pragma unroll
    for (int at = 0; at < 4; ++at) {
        float4 bv = *(const float4*)&b1f[fb + at * 16 + q * 4];
#pragma unroll
        for (int jt = 0; jt < 6; ++jt) {
            int node = jt * 16 + ln15;
            float v0 = fmaxf(acc[jt][at][0] + bv.x, 0.0f);
            float v1 = fmaxf(acc[jt][at][1] + bv.y, 0.0f);
            float v2 = fmaxf(acc[jt][at][2] + bv.z, 0.0f);
            float v3 = fmaxf(acc[jt][at][3] + bv.w, 0.0f);
            *(uint2*)&sG[node * HS + fb + at * 16 + q * 4] =
                make_uint2(packRNE(v0, v1), packRNE(v2, v3));
        }
    }
    __syncthreads();   // (3)

    // ---------- GEMM2: t2 = h @ W2' ----------
#pragma unroll
    for (int kc = 0; kc < 4; ++kc) {
        bf16x8 a6[6], w2f[4];
#pragma unroll
        for (int mt = 0; mt < 6; ++mt)
            a6[mt] = *(const bf16x8*)&sG[(mt * 16 + ln15) * HS + kc * 32 + k0];
#pragma unroll
        for (int nt = 0; nt < 4; ++nt)
            w2f[nt] = *(const bf16x8*)&w2r[(fb + nt * 16 + ln15) * 128 + kc * 32 + k0];
        if (kc == 0) {
#pragma unroll
            for (int mt = 0; mt < 6; ++mt)
#pragma unroll
                for (int nt = 0; nt < 4; ++nt)
                    acc[mt][nt] = __builtin_amdgcn_mfma_f32_16x16x32_bf16(a6[mt], w2f[nt], z4, 0, 0, 0);
        } else {
#pragma unroll
            for (int mt = 0; mt < 6; ++mt)
#pragma unroll
                for (int nt = 0; nt < 4; ++nt)
                    acc[mt][nt] = __builtin_amdgcn_mfma_f32_16x16x32_bf16(a6[mt], w2f[nt], acc[mt][nt], 0, 0, 0);
        }
    }
    __syncthreads();   // (4) h reads done before aliased t2^T writes

#pragma unroll
    for (int mt = 0; mt < 6; ++mt)
#pragma unroll
        for (int nt = 0; nt < 4; ++nt) {
            int f = fb + nt * 16 + ln15;
            int cellb = mt * 16 + q * 4;
            *(uint2*)&sG[f * TS + cellb] =
                make_uint2(packRNE(acc[mt][nt][0], acc[mt][nt][1]),
                           packRNE(acc[mt][nt][2], acc[mt][nt][3]));
        }
    __syncthreads();   // (5)

    // ---------- AGG2: h2^T = t2^T @ S ; relu(+b2), fused pool (raw sums) ----------
#pragma unroll
    for (int kc = 0; kc < 3; ++kc) {
        bf16x8 afr[4], sfb[6];
#pragma unroll
        for (int at = 0; at < 4; ++at)
            afr[at] = *(const bf16x8*)&sG[(fb + at * 16 + ln15) * TS + kc * 32 + k0];
#pragma unroll
        for (int jt = 0; jt < 6; ++jt)
            sfb[jt] = *(const bf16x8*)&sr[((jt * 3 + kc) * 64 + lane) * 8];
        if (kc == 0) {
#pragma unroll
            for (int jt = 0; jt < 6; ++jt)
#pragma unroll
                for (int at = 0; at < 4; ++at)
                    acc[jt][at] = __builtin_amdgcn_mfma_f32_16x16x32_bf16(afr[at], sfb[jt], z4, 0, 0, 0);
        } else {
#pragma unroll
            for (int jt = 0; jt < 6; ++jt)
#pragma unroll
                for (int at = 0; at < 4; ++at)
                    acc[jt][at] = __builtin_amdgcn_mfma_f32_16x16x32_bf16(afr[at], sfb[jt], acc[jt][at], 0, 0, 0);
        }
    }
#pragma unroll
    for (int at = 0; at < 4; ++at) {
        float4 bv = *(const float4*)&b2f[fb + at * 16 + q * 4];
        float s0 = 0.f, s1 = 0.f, s2 = 0.f, s3 = 0.f;
#pragma unroll
        for (int jt = 0; jt < 6; ++jt) {
            int node = jt * 16 + ln15;
            if (node < 81) {
                s0 += fmaxf(acc[jt][at][0] + bv.x, 0.0f);
                s1 += fmaxf(acc[jt][at][1] + bv.y, 0.0f);
                s2 += fmaxf(acc[jt][at][2] + bv.z, 0.0f);
                s3 += fmaxf(acc[jt][at][3] + bv.w, 0.0f);
            }
        }
#pragma unroll
        for (int off = 1; off < 16; off <<= 1) {   // reduce over the 16 node-lanes
            s0 += __shfl_xor(s0, off);
            s1 += __shfl_xor(s1, off);
            s2 += __shfl_xor(s2, off);
            s3 += __shfl_xor(s3, off);
        }
        if (ln15 == 0) {
            float4 v = {s0, s1, s2, s3};
            *(float4*)&sPool[fb + at * 16 + q * 4] = v;   // raw sums; 1/81 in whf
        }
    }
    __syncthreads();   // (6)

    // ---------- heads: 104 outputs ----------
    if (tid < 104) {
        float a = bhf[tid];
        const float4* wrow = (const float4*)(whf + tid * 128);
        const float4* sp4  = (const float4*)sPool;
#pragma unroll 8
        for (int i = 0; i < 32; ++i) {
            float4 wv = wrow[i];
            float4 pv = sp4[i];
            a += pv.x * wv.x + pv.y * wv.y + pv.z * wv.z + pv.w * wv.w;
        }
        int o = tid, oo; size_t off;
        if (o < 4)       { oo = o;      off = (size_t)g * 4 + oo; }
        else if (o < 85) { oo = o - 4;  off = (size_t)nB * 4  + (size_t)g * 81 + oo; }
        else if (o < 94) { oo = o - 85; off = (size_t)nB * 85 + (size_t)g * 9  + oo; }
        else             { oo = o - 94; off = (size_t)nB * 94 + (size_t)g * 10 + oo; }
        if (f32) ((float*)out)[off] = a;
        else     ((unsigned short*)out)[off] = f2b(a);
    }
}

extern "C" void kernel_launch(void* const* d_in, const int* in_sizes, int n_in,
                              void* d_out, int out_size, void* d_ws, size_t ws_size,
                              hipStream_t stream) {
    // setup_inputs order: x, edge_index, batch, W1, b1, W2, b2, Wa, ba, Wc, bc, Wn, bn, Wt, bt
    const void* x  = d_in[0];
    int nB = in_sizes[2] / 81;
    if (nB <= 0) return;

    char* ws = (char*)d_ws;
    hipLaunchKernelGGL(k_repack, dim3(170), dim3(256), 0, stream,
                       x, d_in[3], d_in[4], d_in[5], d_in[6],
                       d_in[7], d_in[8], d_in[9], d_in[10],
                       d_in[11], d_in[12], d_in[13], d_in[14], ws);
    hipLaunchKernelGGL(sudoku_gnn, dim3(nB), dim3(128), 0, stream,
                       x, (const char*)ws, d_out, nB);
}

// Round 8
// 150.529 us; speedup vs baseline: 1.0747x; 1.0241x over previous
//
#include <hip/hip_runtime.h>
#include <hip/hip_bf16.h>

// Two sudoku graphs per 256-thread block (R5 structure, best measured).
// S = (A+I) symmetric, deg==21 -> 1/21 folded into W1/W2; 1/81 folded into
// head weights. All matmuls bf16 MFMA. Dataflow per graph (aliased LDS buf):
//   GEMM1 x@W1' -> t1^T[f][cell] -> AGG1 t1^T@S -> h[node][f] (relu+b1)
//   GEMM2 h@W2' -> t2^T[f][cell] -> AGG2 t2^T@S -> pool -> heads
// Every handoff is b64-write / b128-read. S fragments persistent in regs.
typedef __attribute__((ext_vector_type(8))) short bf16x8;
typedef __attribute__((ext_vector_type(4))) float f32x4;

__device__ __forceinline__ unsigned short f2b(float f) {
    __hip_bfloat16 h = __float2bfloat16(f);
    return __builtin_bit_cast(unsigned short, h);
}
__device__ __forceinline__ float b2f(unsigned short u) {
    unsigned v = ((unsigned)u) << 16;
    return __builtin_bit_cast(float, v);
}
__device__ __forceinline__ float ldf(const void* p, int idx, bool f32) {
    return f32 ? ((const float*)p)[idx] : b2f(((const unsigned short*)p)[idx]);
}
__device__ __forceinline__ unsigned short ldb(const void* p, int idx, bool f32) {
    return f32 ? f2b(((const float*)p)[idx]) : ((const unsigned short*)p)[idx];
}
// branchless RNE pack of two finite floats -> bf16x2
__device__ __forceinline__ unsigned packRNE(float x, float y) {
    unsigned a = __builtin_bit_cast(unsigned, x);
    unsigned b = __builtin_bit_cast(unsigned, y);
    a += 0x7fffu + ((a >> 16) & 1u);
    b += 0x7fffu + ((b >> 16) & 1u);
    return (a >> 16) | (b & 0xffff0000u);
}
__device__ __forceinline__ bool sniff_f32(const void* x) {
    const unsigned* p = (const unsigned*)x;
    int wild = 0;
#pragma unroll
    for (int i = 0; i < 16; ++i) {
        unsigned e = (p[i] >> 7) & 0xFF;
        wild += (e != 0 && (e < 0x68 || e > 0x90)) ? 1 : 0;
    }
    return wild > 8;
}

// ---- ws layout (bytes) ----
#define WS_FLAG   0         // 1 int: 1 = fp32 inputs
#define WS_B1F    16        // 128 f32
#define WS_B2F    528       // 128 f32
#define WS_BHF    1040      // 104 f32
#define WS_W1R    1536      // 128*32 bf16   [f][k]   (pre-scaled 1/21)
#define WS_W2R    9728      // 128*128 bf16  [f][k]   (pre-scaled 1/21)
#define WS_SR     42496     // 18*64*8 bf16  [(jt*3+kc)*64+lane][j]
#define WS_WH     60928     // 104*128 f32   [o][f]   (pre-scaled 1/81)

__global__ void k_repack(const void* __restrict__ x,
                         const void* __restrict__ W1, const void* __restrict__ b1,
                         const void* __restrict__ W2, const void* __restrict__ b2,
                         const void* __restrict__ Wa, const void* __restrict__ ba,
                         const void* __restrict__ Wc, const void* __restrict__ bc,
                         const void* __restrict__ Wn, const void* __restrict__ bn,
                         const void* __restrict__ Wt, const void* __restrict__ bt,
                         char* __restrict__ ws) {
    const bool f32 = sniff_f32(x);
    const float inv21 = 1.0f / 21.0f;
    if (blockIdx.x == 0 && threadIdx.x == 0) *(int*)(ws + WS_FLAG) = f32 ? 1 : 0;
    int idx = blockIdx.x * blockDim.x + threadIdx.x;
    if (idx < 4096) {                         // w1r [f][k], scaled 1/21
        int f = idx >> 5, k = idx & 31;
        unsigned short v = (k < 10) ? f2b(ldf(W1, k * 128 + f, f32) * inv21) : (unsigned short)0;
        ((unsigned short*)(ws + WS_W1R))[idx] = v;
        return;
    }
    idx -= 4096;
    if (idx < 16384) {                        // w2r [f][k], scaled 1/21
        int f = idx >> 7, k = idx & 127;
        ((unsigned short*)(ws + WS_W2R))[idx] = f2b(ldf(W2, k * 128 + f, f32) * inv21);
        return;
    }
    idx -= 16384;
    if (idx < 9216) {                         // S fragments
        int fi = idx >> 9, rem = idx & 511;
        int lane = rem >> 3, j = rem & 7;
        int mi = fi / 3, kc = fi - mi * 3;
        int node = mi * 16 + (lane & 15);
        int cell = kc * 32 + ((lane >> 4) << 3) + j;
        bool adj = false;
        if (node < 81 && cell < 81) {
            int ni = node / 9, nj = node % 9;
            int ci = cell / 9, cj = cell % 9;
            adj = (ni == ci) || (nj == cj) ||
                  ((ni / 3 == ci / 3) && (nj / 3 == cj / 3));
        }
        ((unsigned short*)(ws + WS_SR))[idx] = adj ? (unsigned short)0x3F80 : (unsigned short)0;
        return;
    }
    idx -= 9216;
    if (idx < 13312) {                        // head weights (f32), scaled 1/81
        int o = idx >> 7, f = idx & 127;
        const void* W; int oo, dim;
        if (o < 4)       { W = Wa; oo = o;      dim = 4;  }
        else if (o < 85) { W = Wc; oo = o - 4;  dim = 81; }
        else if (o < 94) { W = Wn; oo = o - 85; dim = 9;  }
        else             { W = Wt; oo = o - 94; dim = 10; }
        ((float*)(ws + WS_WH))[idx] = ldf(W, f * dim + oo, f32) * (1.0f / 81.0f);
        return;
    }
    idx -= 13312;
    if (idx < 360) {                          // biases (unscaled)
        float v;
        if (idx < 128)      v = ldf(b1, idx, f32);
        else if (idx < 256) v = ldf(b2, idx - 128, f32);
        else {
            int o = idx - 256;
            if (o < 4)       v = ldf(ba, o, f32);
            else if (o < 85) v = ldf(bc, o - 4, f32);
            else if (o < 94) v = ldf(bn, o - 85, f32);
            else             v = ldf(bt, o - 94, f32);
        }
        if (idx < 128)      ((float*)(ws + WS_B1F))[idx] = v;
        else if (idx < 256) ((float*)(ws + WS_B2F))[idx - 128] = v;
        else                ((float*)(ws + WS_BHF))[idx - 256] = v;
    }
}

#define TS 104   // t^T view: [f:128][cell:96+pad]  -> 13312 shorts
#define HS 136   // h view:   [node:96][f:128+pad]  -> 13056 shorts (aliased)

__global__ __launch_bounds__(256, 2) void sudoku_gnn(
    const void* __restrict__ x, const char* __restrict__ ws,
    void* __restrict__ out, int nB)
{
    __shared__ __attribute__((aligned(16))) unsigned short sG[2][13312]; // per-graph t^T/h (aliased)

    const bool f32 = (*(const int*)(ws + WS_FLAG)) != 0;
    const unsigned short* w1r = (const unsigned short*)(ws + WS_W1R);
    const unsigned short* w2r = (const unsigned short*)(ws + WS_W2R);
    const unsigned short* sr  = (const unsigned short*)(ws + WS_SR);
    const float* b1f = (const float*)(ws + WS_B1F);
    const float* b2f = (const float*)(ws + WS_B2F);
    const float* bhf = (const float*)(ws + WS_BHF);
    const float* whf = (const float*)(ws + WS_WH);

    const int tid  = threadIdx.x;
    const int wave = tid >> 6;
    const int lane = tid & 63;
    const int ln15 = lane & 15;
    const int q    = lane >> 4;
    const int k0   = q * 8;
    const int mtb  = (wave & 1) * 3;      // node-half tiles (3 x 16 nodes)
    const int nb   = (wave & 1) * 48;
    const int fb   = (wave >> 1) * 64;    // feature half (4 x 16 f)
    const int g0   = blockIdx.x * 2;
    const bool hasB = (g0 + 1 < nB);
    const int g1   = hasB ? (g0 + 1) : g0;

    // ---- persistent S fragments (B-operand; S symmetric) ----
    bf16x8 sfr[3][3];
#pragma unroll
    for (int kc = 0; kc < 3; ++kc)
#pragma unroll
        for (int jt = 0; jt < 3; ++jt)
            sfr[kc][jt] = *(const bf16x8*)&sr[(((mtb + jt) * 3 + kc) * 64 + lane) * 8];
    // W1' B-frags
    bf16x8 w1f[4];
#pragma unroll
    for (int nt = 0; nt < 4; ++nt)
        w1f[nt] = *(const bf16x8*)&w1r[(fb + nt * 16 + ln15) * 32 + k0];

    // ---- x A-frags direct from global (one-time; q>=2 lanes are K-pad) ----
    bf16x8 xf[2][3];
#pragma unroll
    for (int gg = 0; gg < 2; ++gg)
#pragma unroll
        for (int mt = 0; mt < 3; ++mt) {
            int node = (mtb + mt) * 16 + ln15;
            int g = gg ? g1 : g0;
            bf16x8 v = {0, 0, 0, 0, 0, 0, 0, 0};
            if (node < 81) {
                int base = (g * 81 + node) * 10;
                if (q == 0) {
#pragma unroll
                    for (int jj = 0; jj < 8; ++jj) v[jj] = (short)ldb(x, base + jj, f32);
                } else if (q == 1) {
                    v[0] = (short)ldb(x, base + 8, f32);
                    v[1] = (short)ldb(x, base + 9, f32);
                }
            }
            xf[gg][mt] = v;
        }

    const f32x4 z4 = {0.f, 0.f, 0.f, 0.f};
    f32x4 acc[2][3][4];

    // ---------- GEMM1: t1 = x @ W1' ; write t1^T[f][cell] ----------
#pragma unroll
    for (int gg = 0; gg < 2; ++gg)
#pragma unroll
        for (int mt = 0; mt < 3; ++mt)
#pragma unroll
            for (int nt = 0; nt < 4; ++nt)
                acc[gg][mt][nt] = __builtin_amdgcn_mfma_f32_16x16x32_bf16(xf[gg][mt], w1f[nt], z4, 0, 0, 0);
#pragma unroll
    for (int gg = 0; gg < 2; ++gg)
#pragma unroll
        for (int mt = 0; mt < 3; ++mt)
#pragma unroll
            for (int nt = 0; nt < 4; ++nt) {
                int f = fb + nt * 16 + ln15;
                int cellb = (mtb + mt) * 16 + q * 4;
                *(uint2*)&sG[gg][f * TS + cellb] =
                    make_uint2(packRNE(acc[gg][mt][nt][0], acc[gg][mt][nt][1]),
                               packRNE(acc[gg][mt][nt][2], acc[gg][mt][nt][3]));
            }
    __syncthreads();   // (1) t1 visible

    // ---------- AGG1: h1^T = t1^T @ S ----------
#pragma unroll
    for (int kc = 0; kc < 3; ++kc) {
        bf16x8 afr[2][4];
#pragma unroll
        for (int gg = 0; gg < 2; ++gg)
#pragma unroll
            for (int at = 0; at < 4; ++at)
                afr[gg][at] = *(const bf16x8*)&sG[gg][(fb + at * 16 + ln15) * TS + kc * 32 + k0];
        if (kc == 0) {
#pragma unroll
            for (int gg = 0; gg < 2; ++gg)
#pragma unroll
                for (int at = 0; at < 4; ++at)
#pragma unroll
                    for (int jt = 0; jt < 3; ++jt)
                        acc[gg][jt][at] = __builtin_amdgcn_mfma_f32_16x16x32_bf16(afr[gg][at], sfr[0][jt], z4, 0, 0, 0);
        } else {
#pragma unroll
            for (int gg = 0; gg < 2; ++gg)
#pragma unroll
                for (int at = 0; at < 4; ++at)
#pragma unroll
                    for (int jt = 0; jt < 3; ++jt)
                        acc[gg][jt][at] = __builtin_amdgcn_mfma_f32_16x16x32_bf16(afr[gg][at], sfr[kc][jt], acc[gg][jt][at], 0, 0, 0);
        }
    }
    __syncthreads();   // (2) t1 reads done before aliased h writes

    // epilogue: h = relu(agg + b1)   (1/21 folded into W1')
#pragma unroll
    for (int gg = 0; gg < 2; ++gg)
#pragma unroll
        for (int at = 0; at < 4; ++at) {
            float4 bv = *(const float4*)&b1f[fb + at * 16 + q * 4];
#pragma unroll
            for (int jt = 0; jt < 3; ++jt) {
                int node = nb + jt * 16 + ln15;
                float v0 = fmaxf(acc[gg][jt][at][0] + bv.x, 0.0f);
                float v1 = fmaxf(acc[gg][jt][at][1] + bv.y, 0.0f);
                float v2 = fmaxf(acc[gg][jt][at][2] + bv.z, 0.0f);
                float v3 = fmaxf(acc[gg][jt][at][3] + bv.w, 0.0f);
                *(uint2*)&sG[gg][node * HS + fb + at * 16 + q * 4] =
                    make_uint2(packRNE(v0, v1), packRNE(v2, v3));
            }
        }
    __syncthreads();   // (3) h visible

    // ---------- GEMM2: t2 = h @ W2' ----------
#pragma unroll
    for (int kc = 0; kc < 4; ++kc) {
        bf16x8 w2f[4], a3[2][3];
#pragma unroll
        for (int nt = 0; nt < 4; ++nt)
            w2f[nt] = *(const bf16x8*)&w2r[(fb + nt * 16 + ln15) * 128 + kc * 32 + k0];
#pragma unroll
        for (int gg = 0; gg < 2; ++gg)
#pragma unroll
            for (int mt = 0; mt < 3; ++mt)
                a3[gg][mt] = *(const bf16x8*)&sG[gg][((mtb + mt) * 16 + ln15) * HS + kc * 32 + k0];
        if (kc == 0) {
#pragma unroll
            for (int gg = 0; gg < 2; ++gg)
#pragma unroll
                for (int mt = 0; mt < 3; ++mt)
#pragma unroll
                    for (int nt = 0; nt < 4; ++nt)
                        acc[gg][mt][nt] = __builtin_amdgcn_mfma_f32_16x16x32_bf16(a3[gg][mt], w2f[nt], z4, 0, 0, 0);
        } else {
#pragma unroll
            for (int gg = 0; gg < 2; ++gg)
#pragma unroll
                for (int mt = 0; mt < 3; ++mt)
#pragma unroll
                    for (int nt = 0; nt < 4; ++nt)
                        acc[gg][mt][nt] = __builtin_amdgcn_mfma_f32_16x16x32_bf16(a3[gg][mt], w2f[nt], acc[gg][mt][nt], 0, 0, 0);
        }
    }
    __syncthreads();   // (4) h reads done before aliased t2 writes

#pragma unroll
    for (int gg = 0; gg < 2; ++gg)
#pragma unroll
        for (int mt = 0; mt < 3; ++mt)
#pragma unroll
            for (int nt = 0; nt < 4; ++nt) {
                int f = fb + nt * 16 + ln15;
                int cellb = (mtb + mt) * 16 + q * 4;
                *(uint2*)&sG[gg][f * TS + cellb] =
                    make_uint2(packRNE(acc[gg][mt][nt][0], acc[gg][mt][nt][1]),
                               packRNE(acc[gg][mt][nt][2], acc[gg][mt][nt][3]));
            }
    __syncthreads();   // (5) t2 visible

    // ---------- AGG2: h2^T = t2^T @ S ; relu(+b2), fused pool (raw sums) ----------
#pragma unroll
    for (int kc = 0; kc < 3; ++kc) {
        bf16x8 afr[2][4];
#pragma unroll
        for (int gg = 0; gg < 2; ++gg)
#pragma unroll
            for (int at = 0; at < 4; ++at)
                afr[gg][at] = *(const bf16x8*)&sG[gg][(fb + at * 16 + ln15) * TS + kc * 32 + k0];
        if (kc == 0) {
#pragma unroll
            for (int gg = 0; gg < 2; ++gg)
#pragma unroll
                for (int at = 0; at < 4; ++at)
#pragma unroll
                    for (int jt = 0; jt < 3; ++jt)
                        acc[gg][jt][at] = __builtin_amdgcn_mfma_f32_16x16x32_bf16(afr[gg][at], sfr[0][jt], z4, 0, 0, 0);
        } else {
#pragma unroll
            for (int gg = 0; gg < 2; ++gg)
#pragma unroll
                for (int at = 0; at < 4; ++at)
#pragma unroll
                    for (int jt = 0; jt < 3; ++jt)
                        acc[gg][jt][at] = __builtin_amdgcn_mfma_f32_16x16x32_bf16(afr[gg][at], sfr[kc][jt], acc[gg][jt][at], 0, 0, 0);
        }
    }
    // per-wave partial pools in registers
    float ps[2][4][4];   // [gg][at][r]
#pragma unroll
    for (int gg = 0; gg < 2; ++gg)
#pragma unroll
        for (int at = 0; at < 4; ++at) {
            float4 bv = *(const float4*)&b2f[fb + at * 16 + q * 4];
            float s0 = 0.f, s1 = 0.f, s2 = 0.f, s3 = 0.f;
#pragma unroll
            for (int jt = 0; jt < 3; ++jt) {
                int node = nb + jt * 16 + ln15;
                if (node < 81) {
                    s0 += fmaxf(acc[gg][jt][at][0] + bv.x, 0.0f);
                    s1 += fmaxf(acc[gg][jt][at][1] + bv.y, 0.0f);
                    s2 += fmaxf(acc[gg][jt][at][2] + bv.z, 0.0f);
                    s3 += fmaxf(acc[gg][jt][at][3] + bv.w, 0.0f);
                }
            }
#pragma unroll
            for (int off = 1; off < 16; off <<= 1) {
                s0 += __shfl_xor(s0, off);
                s1 += __shfl_xor(s1, off);
                s2 += __shfl_xor(s2, off);
                s3 += __shfl_xor(s3, off);
            }
            ps[gg][at][0] = s0; ps[gg][at][1] = s1; ps[gg][at][2] = s2; ps[gg][at][3] = s3;
        }
    __syncthreads();   // (6) all sG reads done -> buffer reusable as f32 scratch

    // partial pools into dead sG region: sPart[gg][half*128 + f] (f32)
#pragma unroll
    for (int gg = 0; gg < 2; ++gg) {
        float* sPart = (float*)&sG[gg][0];
        if (ln15 == 0) {
#pragma unroll
            for (int at = 0; at < 4; ++at) {
                float4 v = {ps[gg][at][0], ps[gg][at][1], ps[gg][at][2], ps[gg][at][3]};
                *(float4*)&sPart[(wave & 1) * 128 + fb + at * 16 + q * 4] = v;
            }
        }
    }
    __syncthreads();   // (7)
    {
        int gg = tid >> 7, f = tid & 127;
        float* sPart = (float*)&sG[gg][0];
        ((float*)&sG[gg][512])[f] = sPart[f] + sPart[128 + f];   // raw sum; 1/81 in whf
    }
    __syncthreads();   // (8)

    // ---------- heads: 104 outputs per graph (A: tid 0..103, B: 128..231) ----------
    {
        int gg = tid >> 7;
        int o  = tid & 127;
        int g  = gg ? (g0 + 1) : g0;
        if (o < 104 && (gg == 0 || hasB)) {
            float a = bhf[o];
            const float4* wrow = (const float4*)(whf + o * 128);
            const float4* sp4  = (const float4*)&sG[gg][512];
#pragma unroll 8
            for (int i = 0; i < 32; ++i) {
                float4 wv = wrow[i];
                float4 pv = sp4[i];
                a += pv.x * wv.x + pv.y * wv.y + pv.z * wv.z + pv.w * wv.w;
            }
            int oo; size_t off;
            if (o < 4)       { oo = o;      off = (size_t)g * 4 + oo; }
            else if (o < 85) { oo = o - 4;  off = (size_t)nB * 4  + (size_t)g * 81 + oo; }
            else if (o < 94) { oo = o - 85; off = (size_t)nB * 85 + (size_t)g * 9  + oo; }
            else             { oo = o - 94; off = (size_t)nB * 94 + (size_t)g * 10 + oo; }
            if (f32) ((float*)out)[off] = a;
            else     ((unsigned short*)out)[off] = f2b(a);
        }
    }
}

extern "C" void kernel_launch(void* const* d_in, const int* in_sizes, int n_in,
                              void* d_out, int out_size, void* d_ws, size_t ws_size,
                              hipStream_t stream) {
    // setup_inputs order: x, edge_index, batch, W1, b1, W2, b2, Wa, ba, Wc, bc, Wn, bn, Wt, bt
    const void* x  = d_in[0];
    int nB = in_sizes[2] / 81;
    if (nB <= 0) return;

    char* ws = (char*)d_ws;
    hipLaunchKernelGGL(k_repack, dim3(170), dim3(256), 0, stream,
                       x, d_in[3], d_in[4], d_in[5], d_in[6],
                       d_in[7], d_in[8], d_in[9], d_in[10],
                       d_in[11], d_in[12], d_in[13], d_in[14], ws);
    hipLaunchKernelGGL(sudoku_gnn, dim3((nB + 1) / 2), dim3(256), 0, stream,
                       x, (const char*)ws, d_out, nB);
}